// Round 16
// baseline (355.996 us; speedup 1.0000x reference)
//
#include <hip/hip_runtime.h>
#include <hip/hip_bf16.h>

#define NB  16
#define NN  16384
#define NC  256
#define NPP 128
#define NSS 16

#define FTH 1024  // fps threads per block (16 waves = 4 waves/SIMD)

// ---------------- FPS: one block per batch (r10 layout, 16-wave combine) --
// Prologue: grid-stride weight transpose (formulas identical to the former
// transpose_kernel; consumed only by mlp_kernel which launches after fps
// completes -> no intra-kernel sync needed). Saves one dispatch + gap.
// Exact numpy semantics: d = ((dx*dx + dy*dy) + dz*dz), per-op rounding,
// argmax tie-break = lowest index via packed u64 max: pk = valbits<<32 | ~idx.
// Floor notes (r2-r15): 12 structural variants all 1.73-1.94 us/iter; j-loop
// is within ~25% of the f32-op rate (1408 cyc ideal; v_pk_*_f32 adds no
// throughput on CDNA4 -- 157.3 TF peak IS the scalar-FMA rate); multi-block
// exchange 8x worse (cross-XCD coherence, r13). Sequential-argmax floor.
__global__ __attribute__((amdgpu_flat_work_group_size(1024, 1024)))
void fps_kernel(
    const float* __restrict__ xyz,
    const float* __restrict__ W1, const float* __restrict__ W2,
    const float* __restrict__ W3, const float* __restrict__ Wm,
    float* __restrict__ W1T, float* __restrict__ W2T,
    float* __restrict__ W3T, float* __restrict__ WmT,
    float* __restrict__ centers, float* __restrict__ out_xyz,
    float* __restrict__ out_indf) {
  int b = blockIdx.x;
  int t = threadIdx.x;
  // ---- folded weight transpose (grid-stride over 16 blocks) ----
  for (int i = b * FTH + t; i < 128 * 259; i += NB * FTH) {
    int o = i / 259, c = i - o * 259;
    W1T[c * 128 + o] = W1[i];
  }
  for (int i = b * FTH + t; i < 128 * 128; i += NB * FTH) {
    int o = i >> 7, c = i & 127;
    W2T[c * 128 + o] = W2[i];
    W3T[c * 128 + o] = W3[i];
    WmT[c * 128 + o] = Wm[i];
    WmT[16384 + c * 128 + o] = Wm[16384 + i];
  }
  const float* px = xyz + (size_t)b * (NN * 3);
  __shared__ float2 sxy[NN / 2];               // 64 KB: points 8192..16383
  __shared__ unsigned long long cand[2][16];
  __shared__ float4 hist[NPP];                 // per-iter (cx,cy,cz,idx)
  float Xr[8], Yr[8], Zr[16], MD[16];
#pragma unroll
  for (int j = 0; j < 16; ++j) {
    int n = t + (j << 10);
    float x = px[n * 3 + 0];
    float y = px[n * 3 + 1];
    float z = px[n * 3 + 2];
    asm volatile("" : "+v"(z));                // z: reg-resident, no re-load
    if (j < 8) {
      asm volatile("" : "+v"(x), "+v"(y));     // first 8 pts: xy in regs
      Xr[j] = x; Yr[j] = y;
    } else {
      sxy[n - 8192] = make_float2(x, y);       // last 8 pts: xy in LDS
    }
    Zr[j] = z;
    MD[j] = 1e10f;
  }
  float cx = px[0], cy = px[1], cz = px[2];
  if (t == 0) hist[0] = make_float4(cx, cy, cz, 0.0f);
  __syncthreads();
  for (int it = 1; it < NPP; ++it) {
    float bv = -1.0f;
    int bi = 0;
#pragma unroll
    for (int j = 0; j < 8; ++j) {              // register points
      float dx = __fsub_rn(Xr[j], cx);
      float dy = __fsub_rn(Yr[j], cy);
      float dz = __fsub_rn(Zr[j], cz);
      float d  = __fadd_rn(__fadd_rn(__fmul_rn(dx, dx), __fmul_rn(dy, dy)),
                           __fmul_rn(dz, dz));
      float m = fminf(MD[j], d);
      MD[j] = m;
      if (m > bv) { bv = m; bi = t + (j << 10); }
    }
#pragma unroll
    for (int j = 8; j < 16; ++j) {             // LDS points
      float2 v = sxy[t + ((j - 8) << 10)];
      float dx = __fsub_rn(v.x, cx);
      float dy = __fsub_rn(v.y, cy);
      float dz = __fsub_rn(Zr[j], cz);
      float d  = __fadd_rn(__fadd_rn(__fmul_rn(dx, dx), __fmul_rn(dy, dy)),
                           __fmul_rn(dz, dz));
      float m = fminf(MD[j], d);
      MD[j] = m;
      if (m > bv) { bv = m; bi = t + (j << 10); }
    }
    unsigned long long pk =
        (((unsigned long long)__float_as_uint(bv)) << 32) |
        (unsigned long long)(~(unsigned)bi);
    // ---- wave64 max-reduce: 4x DPP row_ror + swizzle xor16 + shfl xor32 --
#define STEP_ROR(N)                                                         \
    {                                                                       \
      unsigned lo = (unsigned)pk, hi = (unsigned)(pk >> 32);                \
      lo = (unsigned)__builtin_amdgcn_mov_dpp((int)lo, 0x120 | N, 0xF, 0xF, true); \
      hi = (unsigned)__builtin_amdgcn_mov_dpp((int)hi, 0x120 | N, 0xF, 0xF, true); \
      unsigned long long o = ((unsigned long long)hi << 32) | lo;           \
      if (o > pk) pk = o;                                                   \
    }
    STEP_ROR(1) STEP_ROR(2) STEP_ROR(4) STEP_ROR(8)
    {  // lane ^ 16 within 32-lane halves (ds_swizzle BitMode 0x401F)
      unsigned lo = (unsigned)pk, hi = (unsigned)(pk >> 32);
      lo = (unsigned)__builtin_amdgcn_ds_swizzle((int)lo, 0x401F);
      hi = (unsigned)__builtin_amdgcn_ds_swizzle((int)hi, 0x401F);
      unsigned long long o = ((unsigned long long)hi << 32) | lo;
      if (o > pk) pk = o;
    }
    {  // lane ^ 32
      unsigned long long o = __shfl_xor(pk, 32, 64);
      if (o > pk) pk = o;
    }
    int p = it & 1;
    if ((t & 63) == 0) cand[p][t >> 6] = pk;   // 16 waves -> slots 0..15
    __syncthreads();
    // ---- 16-candidate combine: broadcast read + 4 DPP row_ror steps ----
    pk = cand[p][t & 15];
    STEP_ROR(1) STEP_ROR(2) STEP_ROR(4) STEP_ROR(8)
#undef STEP_ROR
    int win = (int)(~(unsigned)(pk & 0xFFFFFFFFull));
    win = __builtin_amdgcn_readfirstlane(win);
    cx = px[win * 3 + 0];                      // uniform scalar loads (L2)
    cy = px[win * 3 + 1];
    cz = px[win * 3 + 2];
    if (t == 0) hist[it] = make_float4(cx, cy, cz, (float)win);
  }
  __syncthreads();
  if (t < NPP) {                               // one-shot output flush
    float4 h = hist[t];
    centers[(b * NPP + t) * 3 + 0] = h.x;
    centers[(b * NPP + t) * 3 + 1] = h.y;
    centers[(b * NPP + t) * 3 + 2] = h.z;
    out_xyz[(b * NPP + t) * 3 + 0] = h.x;
    out_xyz[(b * NPP + t) * 3 + 1] = h.y;
    out_xyz[(b * NPP + t) * 3 + 2] = h.z;
    out_indf[b * NPP + t] = h.w;
  }
}

// ---------------- grouped MLP with FUSED ball query ----------------
// ballq block (b,s) maps 1:1 to mlp block (b,s): wave 0 does the scan
// (identical chunk order / f32 math / tie+tail handling as the former
// standalone kernel), then the block proceeds to gather+MLP.
__device__ __forceinline__ float4 bnrelu4(float4 a, float s, float b) {
  float4 r;
  r.x = fmaxf(fmaf(a.x, s, b), 0.f);
  r.y = fmaxf(fmaf(a.y, s, b), 0.f);
  r.z = fmaxf(fmaf(a.z, s, b), 0.f);
  r.w = fmaxf(fmaf(a.w, s, b), 0.f);
  return r;
}

__device__ __forceinline__ void layer4(const float (*in)[20], int cin,
                                       const float* __restrict__ WT,
                                       const float* __restrict__ sc,
                                       const float* __restrict__ bi,
                                       int o4, int k0,
                                       float4& r0, float4& r1,
                                       float4& r2, float4& r3) {
  float4 a0 = {0.f, 0.f, 0.f, 0.f}, a1 = a0, a2 = a0, a3 = a0;
  for (int c = 0; c < cin; ++c) {
    float4 w  = *(const float4*)(WT + c * 128 + o4);
    float4 gv = *(const float4*)(&in[c][k0]);
    a0.x = fmaf(w.x, gv.x, a0.x); a0.y = fmaf(w.x, gv.y, a0.y);
    a0.z = fmaf(w.x, gv.z, a0.z); a0.w = fmaf(w.x, gv.w, a0.w);
    a1.x = fmaf(w.y, gv.x, a1.x); a1.y = fmaf(w.y, gv.y, a1.y);
    a1.z = fmaf(w.y, gv.z, a1.z); a1.w = fmaf(w.y, gv.w, a1.w);
    a2.x = fmaf(w.z, gv.x, a2.x); a2.y = fmaf(w.z, gv.y, a2.y);
    a2.z = fmaf(w.z, gv.z, a2.z); a2.w = fmaf(w.z, gv.w, a2.w);
    a3.x = fmaf(w.w, gv.x, a3.x); a3.y = fmaf(w.w, gv.y, a3.y);
    a3.z = fmaf(w.w, gv.z, a3.z); a3.w = fmaf(w.w, gv.w, a3.w);
  }
  r0 = bnrelu4(a0, sc[o4 + 0], bi[o4 + 0]);
  r1 = bnrelu4(a1, sc[o4 + 1], bi[o4 + 1]);
  r2 = bnrelu4(a2, sc[o4 + 2], bi[o4 + 2]);
  r3 = bnrelu4(a3, sc[o4 + 3], bi[o4 + 3]);
}

__global__ __launch_bounds__(128) void mlp_kernel(
    const float* __restrict__ xyz, const float* __restrict__ feats,
    const float* __restrict__ centers,
    const float* __restrict__ W1T, const float* __restrict__ W2T,
    const float* __restrict__ W3T, const float* __restrict__ sa_sc,
    const float* __restrict__ sa_bi, float* __restrict__ feat0) {
  int bs = blockIdx.x;
  int b = bs >> 7;
  int s = bs & 127;
  int tid = threadIdx.x;
  __shared__ __align__(16) float g[259][20];   // 20720 B
  __shared__ __align__(16) float h1[128][20];  // 10240 B
  float (*h2)[20] = (float (*)[20]) & g[0][0]; // alias: g dead after layer1
  __shared__ int kidx[NSS];
  __shared__ int coll[NSS];
  __shared__ float ctr[3];
  const float* px = xyz + (size_t)b * (NN * 3);
  if (tid < 3) ctr[tid] = centers[bs * 3 + tid];
  if (tid < 64) {                        // wave 0: ball query scan
    int lane = tid;
    float cx = centers[bs * 3 + 0];
    float cy = centers[bs * 3 + 1];
    float cz = centers[bs * 3 + 2];
    const float rr = 0.09f;  // f32(0.09): identical membership to f64 cmp
    int have = 0;
    for (int c0 = 0; c0 < NN; c0 += 64) {
      int n = c0 + lane;
      float dx = __fsub_rn(px[n * 3 + 0], cx);
      float dy = __fsub_rn(px[n * 3 + 1], cy);
      float dz = __fsub_rn(px[n * 3 + 2], cz);
      float d2 = __fadd_rn(__fadd_rn(__fmul_rn(dx, dx), __fmul_rn(dy, dy)),
                           __fmul_rn(dz, dz));
      bool in = d2 < rr;
      unsigned long long m = __ballot(in);
      if (in) {
        int pos = have + __popcll(m & ((1ull << lane) - 1ull));
        if (pos < NSS) coll[pos] = n;
      }
      have += __popcll(m);
      if (have >= NSS) break;
    }
    int first = coll[0];
    if (lane < NSS) kidx[lane] = (lane < have) ? coll[lane] : first;
  }
  __syncthreads();
  if (tid < NSS) {
    int n = kidx[tid];
    g[0][tid] = __fdiv_rn(__fsub_rn(px[n * 3 + 0], ctr[0]), 0.3f);
    g[1][tid] = __fdiv_rn(__fsub_rn(px[n * 3 + 1], ctr[1]), 0.3f);
    g[2][tid] = __fdiv_rn(__fsub_rn(px[n * 3 + 2], ctr[2]), 0.3f);
  }
#pragma unroll
  for (int cc = 0; cc < 2; ++cc) {
    int c = tid + cc * 128;
    const float* row = feats + ((size_t)b * NC + c) * NN;
#pragma unroll
    for (int k = 0; k < NSS; ++k) g[3 + c][k] = row[kidx[k]];
  }
  __syncthreads();
  int o4 = (tid & 31) * 4;
  int k0 = (tid >> 5) * 4;   // 0,4,8,12
  float4 r0, r1, r2, r3;
  layer4(g, 259, W1T, sa_sc, sa_bi, o4, k0, r0, r1, r2, r3);
  *(float4*)&h1[o4 + 0][k0] = r0;
  *(float4*)&h1[o4 + 1][k0] = r1;
  *(float4*)&h1[o4 + 2][k0] = r2;
  *(float4*)&h1[o4 + 3][k0] = r3;
  __syncthreads();
  layer4(h1, 128, W2T, sa_sc + 128, sa_bi + 128, o4, k0, r0, r1, r2, r3);
  __syncthreads();                       // layer1's g reads done;
  *(float4*)&h2[o4 + 0][k0] = r0;        // safe to overwrite g as h2
  *(float4*)&h2[o4 + 1][k0] = r1;
  *(float4*)&h2[o4 + 2][k0] = r2;
  *(float4*)&h2[o4 + 3][k0] = r3;
  __syncthreads();
  layer4(h2, 128, W3T, sa_sc + 256, sa_bi + 256, o4, k0, r0, r1, r2, r3);
  float m0 = fmaxf(fmaxf(r0.x, r0.y), fmaxf(r0.z, r0.w));
  float m1 = fmaxf(fmaxf(r1.x, r1.y), fmaxf(r1.z, r1.w));
  float m2 = fmaxf(fmaxf(r2.x, r2.y), fmaxf(r2.z, r2.w));
  float m3 = fmaxf(fmaxf(r3.x, r3.y), fmaxf(r3.z, r3.w));
  int kg = tid >> 5;                     // h1 free (last read in layer2)
  h1[o4 + 0][kg] = m0;
  h1[o4 + 1][kg] = m1;
  h1[o4 + 2][kg] = m2;
  h1[o4 + 3][kg] = m3;
  __syncthreads();
  if (tid < 128) {
    float m = fmaxf(fmaxf(h1[tid][0], h1[tid][1]), fmaxf(h1[tid][2], h1[tid][3]));
    feat0[((size_t)b * 128 + tid) * 128 + s] = m;
  }
}

// ---------------- FC heads: (x@Wm + bm)*scale + bias, relu, x2 ----------------
__global__ __launch_bounds__(256) void head_kernel(
    const float* __restrict__ feat0, const float* __restrict__ WmT,
    const float* __restrict__ bm, const float* __restrict__ msc,
    const float* __restrict__ mbi, float* __restrict__ out_feat) {
  int blk = blockIdx.x;
  int b = blk >> 2;
  int sbase = (blk & 3) * 32;
  int tid = threadIdx.x;
  __shared__ float fa[128][36];
  __shared__ float fb[128][36];
  {
    int sj = tid & 31, c0 = tid >> 5;
    for (int c = c0; c < 128; c += 8)
      fa[c][sj] = feat0[((size_t)b * 128 + c) * 128 + sbase + sj];
  }
  __syncthreads();
  int o2 = (tid & 63) * 2, s0 = (tid >> 6) * 8;
  float a0[8], a1[8];
#pragma unroll
  for (int j = 0; j < 8; ++j) { a0[j] = 0.f; a1[j] = 0.f; }
  for (int c = 0; c < 128; ++c) {
    float2 w = *(const float2*)&WmT[c * 128 + o2];
    float4 f0 = *(const float4*)&fa[c][s0];
    float4 f1 = *(const float4*)&fa[c][s0 + 4];
    a0[0] = fmaf(w.x, f0.x, a0[0]); a0[1] = fmaf(w.x, f0.y, a0[1]);
    a0[2] = fmaf(w.x, f0.z, a0[2]); a0[3] = fmaf(w.x, f0.w, a0[3]);
    a0[4] = fmaf(w.x, f1.x, a0[4]); a0[5] = fmaf(w.x, f1.y, a0[5]);
    a0[6] = fmaf(w.x, f1.z, a0[6]); a0[7] = fmaf(w.x, f1.w, a0[7]);
    a1[0] = fmaf(w.y, f0.x, a1[0]); a1[1] = fmaf(w.y, f0.y, a1[1]);
    a1[2] = fmaf(w.y, f0.z, a1[2]); a1[3] = fmaf(w.y, f0.w, a1[3]);
    a1[4] = fmaf(w.y, f1.x, a1[4]); a1[5] = fmaf(w.y, f1.y, a1[5]);
    a1[6] = fmaf(w.y, f1.z, a1[6]); a1[7] = fmaf(w.y, f1.w, a1[7]);
  }
  {
    float c0 = bm[o2], c1 = bm[o2 + 1];
    float t0 = msc[o2], t1 = msc[o2 + 1];
    float q0 = mbi[o2], q1 = mbi[o2 + 1];
#pragma unroll
    for (int j = 0; j < 8; ++j) {
      fb[o2][s0 + j]     = fmaxf(fmaf(a0[j] + c0, t0, q0), 0.f);
      fb[o2 + 1][s0 + j] = fmaxf(fmaf(a1[j] + c1, t1, q1), 0.f);
    }
  }
  __syncthreads();
#pragma unroll
  for (int j = 0; j < 8; ++j) { a0[j] = 0.f; a1[j] = 0.f; }
  for (int c = 0; c < 128; ++c) {
    float2 w = *(const float2*)&WmT[16384 + c * 128 + o2];
    float4 f0 = *(const float4*)&fb[c][s0];
    float4 f1 = *(const float4*)&fb[c][s0 + 4];
    a0[0] = fmaf(w.x, f0.x, a0[0]); a0[1] = fmaf(w.x, f0.y, a0[1]);
    a0[2] = fmaf(w.x, f0.z, a0[2]); a0[3] = fmaf(w.x, f0.w, a0[3]);
    a0[4] = fmaf(w.x, f1.x, a0[4]); a0[5] = fmaf(w.x, f1.y, a0[5]);
    a0[6] = fmaf(w.x, f1.z, a0[6]); a0[7] = fmaf(w.x, f1.w, a0[7]);
    a1[0] = fmaf(w.y, f0.x, a1[0]); a1[1] = fmaf(w.y, f0.y, a1[1]);
    a1[2] = fmaf(w.y, f0.z, a1[2]); a1[3] = fmaf(w.y, f0.w, a1[3]);
    a1[4] = fmaf(w.y, f1.x, a1[4]); a1[5] = fmaf(w.y, f1.y, a1[5]);
    a1[6] = fmaf(w.y, f1.z, a1[6]); a1[7] = fmaf(w.y, f1.w, a1[7]);
  }
  {
    float c0 = bm[128 + o2], c1 = bm[128 + o2 + 1];
    float t0 = msc[128 + o2], t1 = msc[128 + o2 + 1];
    float q0 = mbi[128 + o2], q1 = mbi[128 + o2 + 1];
    float4 v0a, v0b, v1a, v1b;
    v0a.x = fmaxf(fmaf(a0[0] + c0, t0, q0), 0.f);
    v0a.y = fmaxf(fmaf(a0[1] + c0, t0, q0), 0.f);
    v0a.z = fmaxf(fmaf(a0[2] + c0, t0, q0), 0.f);
    v0a.w = fmaxf(fmaf(a0[3] + c0, t0, q0), 0.f);
    v0b.x = fmaxf(fmaf(a0[4] + c0, t0, q0), 0.f);
    v0b.y = fmaxf(fmaf(a0[5] + c0, t0, q0), 0.f);
    v0b.z = fmaxf(fmaf(a0[6] + c0, t0, q0), 0.f);
    v0b.w = fmaxf(fmaf(a0[7] + c0, t0, q0), 0.f);
    v1a.x = fmaxf(fmaf(a1[0] + c1, t1, q1), 0.f);
    v1a.y = fmaxf(fmaf(a1[1] + c1, t1, q1), 0.f);
    v1a.z = fmaxf(fmaf(a1[2] + c1, t1, q1), 0.f);
    v1a.w = fmaxf(fmaf(a1[3] + c1, t1, q1), 0.f);
    v1b.x = fmaxf(fmaf(a1[4] + c1, t1, q1), 0.f);
    v1b.y = fmaxf(fmaf(a1[5] + c1, t1, q1), 0.f);
    v1b.z = fmaxf(fmaf(a1[6] + c1, t1, q1), 0.f);
    v1b.w = fmaxf(fmaf(a1[7] + c1, t1, q1), 0.f);
    float* p0 = &out_feat[((size_t)b * 128 + o2) * 128 + sbase + s0];
    float* p1 = &out_feat[((size_t)b * 128 + o2 + 1) * 128 + sbase + s0];
    *(float4*)p0 = v0a;
    *(float4*)(p0 + 4) = v0b;
    *(float4*)p1 = v1a;
    *(float4*)(p1 + 4) = v1b;
  }
}

extern "C" void kernel_launch(void* const* d_in, const int* in_sizes, int n_in,
                              void* d_out, int out_size, void* d_ws, size_t ws_size,
                              hipStream_t stream) {
  const float* vote_xyz  = (const float*)d_in[0];
  const float* vote_feat = (const float*)d_in[1];
  const float* W1   = (const float*)d_in[2];
  const float* W2   = (const float*)d_in[3];
  const float* W3   = (const float*)d_in[4];
  const float* sasc = (const float*)d_in[5];
  const float* sabi = (const float*)d_in[6];
  const float* Wm   = (const float*)d_in[7];
  const float* bm   = (const float*)d_in[8];
  const float* msc  = (const float*)d_in[9];
  const float* mbi  = (const float*)d_in[10];

  float* out = (float*)d_out;
  float* out_xyz  = out;                    // B*NP*3   = 6144
  float* out_feat = out + 6144;             // B*128*NP = 262144
  float* out_indf = out + 6144 + 262144;    // B*NP     = 2048

  char* ws = (char*)d_ws;
  float* centers = (float*)(ws + 8192);     //  24 KB
  float* W1T     = (float*)(ws + 163840);   // 132608 B
  float* W2T     = (float*)(ws + 296448);   //  64 KB
  float* W3T     = (float*)(ws + 361984);   //  64 KB
  float* WmT     = (float*)(ws + 427520);   // 128 KB
  float* feat0   = (float*)(ws + 558592);   //   1 MB

  hipLaunchKernelGGL(fps_kernel, dim3(NB), dim3(FTH), 0, stream,
                     vote_xyz, W1, W2, W3, Wm, W1T, W2T, W3T, WmT,
                     centers, out_xyz, out_indf);
  hipLaunchKernelGGL(mlp_kernel, dim3(NB * NPP), dim3(128), 0, stream,
                     vote_xyz, vote_feat, centers, W1T, W2T, W3T,
                     sasc, sabi, feat0);
  hipLaunchKernelGGL(head_kernel, dim3(NB * 4), dim3(256), 0, stream,
                     feat0, WmT, bm, msc, mbi, out_feat);
}